// Round 10
// baseline (435.858 us; speedup 1.0000x reference)
//
#include <hip/hip_runtime.h>
#include <hip/hip_bf16.h>

#define HID 128
#define NRAW 127
#define BSH 8          // 256 nodes per bucket
#define BNODES 256

// Column permutation: all hidden-state tensors (h8, aggbuf, hB, hg) store logical
// column l = ot*16+m at physical position p = m*8+ot; inverse invp(p) = (p&7)*16+(p>>3).
// GEMM weights and the first Wc1 application are k-permuted to match.

typedef __attribute__((ext_vector_type(8))) short short8;
typedef __attribute__((ext_vector_type(4))) float floatx4;
typedef __attribute__((ext_vector_type(2))) float floatx2;

__device__ inline unsigned pack_bf2(float x, float y) {
    unsigned bx = __float_as_uint(x);
    unsigned by = __float_as_uint(y);
    bx += 0x7fffu + ((bx >> 16) & 1u);   // RNE
    by += 0x7fffu + ((by >> 16) & 1u);
    return (bx >> 16) | (by & 0xffff0000u);
}
__device__ inline float bf_lo(unsigned u) { return __uint_as_float(u << 16); }
__device__ inline float bf_hi(unsigned u) { return __uint_as_float(u & 0xffff0000u); }

// ---------------- init: zeros + permuted weight packs ----------------

__global__ void init_kernel(const float* __restrict__ W0, const float* __restrict__ W1,
                            const float* __restrict__ W2, const float* __restrict__ Wc1,
                            unsigned* __restrict__ O0, unsigned* __restrict__ O1,
                            unsigned* __restrict__ O2, float* __restrict__ Wc1p,
                            int* __restrict__ gbucket, float* __restrict__ hg,
                            float* __restrict__ counts, int G) {
    int id = blockIdx.x * blockDim.x + threadIdx.x;
    if (id < 512) gbucket[id] = 0;
    if (id < G * HID) hg[id] = 0.f;
    if (id < G) counts[id] = 0.f;
    if (id < 16384) {   // Wc1 with permuted k for the first head matmul
        int t = id >> 7, p = id & 127;
        Wc1p[id] = Wc1[t * 128 + ((p & 7) * 16 + (p >> 3))];
    }
    if (id < 3 * 8192) {   // GCN weights, bf16, k-permuted
        int sel = id >> 13, l = id & 8191;
        const float* W = sel == 0 ? W0 : (sel == 1 ? W1 : W2);
        unsigned* O = sel == 0 ? O0 : (sel == 1 ? O1 : O2);
        int o = l >> 6, pp = (l & 63) * 2;
        int k0 = (pp & 7) * 16 + (pp >> 3);
        int k1 = ((pp + 1) & 7) * 16 + ((pp + 1) >> 3);
        O[l] = pack_bf2(W[o * 128 + k0], W[o * 128 + k1]);
    }
}

// ---------------- CSR build: bucketed 2-phase counting sort ----------------

__global__ __launch_bounds__(256) void bucket_count_kernel(const int* __restrict__ dst,
                                                           int* __restrict__ gbucket,
                                                           int E, int NB) {
    __shared__ int hist[512];
    int t = threadIdx.x;
    for (int b = t; b < NB; b += 256) hist[b] = 0;
    __syncthreads();
    int base = blockIdx.x * 4096;
    #pragma unroll
    for (int j = 0; j < 16; ++j) {
        int e = base + j * 256 + t;
        if (e < E) atomicAdd(&hist[dst[e] >> BSH], 1);
    }
    __syncthreads();
    for (int b = t; b < NB; b += 256) {
        int v = hist[b];
        if (v) atomicAdd(&gbucket[b], v);
    }
}

__global__ void bucket_scan_kernel(const int* __restrict__ gbucket, int* __restrict__ bstart,
                                   int* __restrict__ gcur, int NB, int E) {
    __shared__ int sm[512];
    int t = threadIdx.x;
    int v = (t < NB) ? gbucket[t] : 0;
    sm[t] = v;
    __syncthreads();
    for (int off = 1; off < 512; off <<= 1) {
        int add = (t >= off) ? sm[t - off] : 0;
        __syncthreads();
        sm[t] += add;
        __syncthreads();
    }
    if (t < NB) {
        int ex = sm[t] - v;
        bstart[t] = ex;
        gcur[t] = ex;
    }
    if (t == 0) bstart[NB] = E;
}

__global__ __launch_bounds__(256) void bucket_scatter_kernel(const int* __restrict__ src,
                                                             const int* __restrict__ dst,
                                                             int* __restrict__ gcur,
                                                             uint2* __restrict__ staging,
                                                             int E, int NB) {
    __shared__ int hist[512];
    __shared__ int base[512];
    int t = threadIdx.x;
    for (int b = t; b < NB; b += 256) hist[b] = 0;
    __syncthreads();
    int s[16], d[16], r[16];
    int e0 = blockIdx.x * 4096;
    #pragma unroll
    for (int j = 0; j < 16; ++j) {
        int e = e0 + j * 256 + t;
        if (e < E) {
            s[j] = src[e];
            d[j] = dst[e];
            r[j] = atomicAdd(&hist[d[j] >> BSH], 1);
        } else d[j] = -1;
    }
    __syncthreads();
    for (int b = t; b < NB; b += 256) {
        int v = hist[b];
        base[b] = v ? atomicAdd(&gcur[b], v) : 0;
    }
    __syncthreads();
    #pragma unroll
    for (int j = 0; j < 16; ++j) {
        if (d[j] >= 0) {
            int b = d[j] >> BSH;
            staging[base[b] + r[j]] = make_uint2((unsigned)s[j], (unsigned)d[j]);
        }
    }
}

__global__ __launch_bounds__(256) void csr_build_kernel(const uint2* __restrict__ staging,
                                                        const int* __restrict__ bstart,
                                                        int* __restrict__ rp, int* __restrict__ csr,
                                                        float* __restrict__ degf,
                                                        int N, int E, int NB) {
    __shared__ int hist[256];
    __shared__ int sm[256];
    __shared__ int excl[256];
    __shared__ int cnt[256];
    int t = threadIdx.x;
    int b = blockIdx.x;
    int nbase = b << BSH;
    int s0 = bstart[b], e1 = bstart[b + 1];
    hist[t] = 0;
    __syncthreads();
    for (int i = s0 + t; i < e1; i += 256) {
        uint2 p = staging[i];
        atomicAdd(&hist[p.y & (BNODES - 1)], 1);
    }
    __syncthreads();
    int h = hist[t];
    sm[t] = h;
    __syncthreads();
    for (int off = 1; off < 256; off <<= 1) {
        int add = (t >= off) ? sm[t - off] : 0;
        __syncthreads();
        sm[t] += add;
        __syncthreads();
    }
    excl[t] = sm[t] - h;
    cnt[t] = 0;
    int n = nbase + t;
    if (n < N) {
        rp[n] = s0 + (sm[t] - h);
        degf[n] = (float)h;
    }
    if (b == NB - 1 && t == 0) rp[N] = E;
    __syncthreads();
    for (int i = s0 + t; i < e1; i += 256) {
        uint2 p = staging[i];
        int dl = p.y & (BNODES - 1);
        int pos = s0 + excl[dl] + atomicAdd(&cnt[dl], 1);
        csr[pos] = (int)p.x;
    }
}

// ---------------- h0 in fp8, permuted layout (logical col0 zeroed; deg exact via degf) ----------------

__global__ void build_h0_kernel(const float* __restrict__ feat,
                                unsigned* __restrict__ h8, int N) {
    int id = blockIdx.x * blockDim.x + threadIdx.x;
    if (id >= N * 32) return;
    int n = id >> 5, c = id & 31;
    const float* fr = feat + (size_t)n * NRAW;
    int base = c >> 1, hb = (c & 1) * 4;
    float f[4];
    #pragma unroll
    for (int j = 0; j < 4; ++j) {
        int l = (hb + j) * 16 + base;   // logical col at physical byte 4c+j
        f[j] = (l == 0) ? 0.f : fr[l - 1];
    }
    unsigned w = __builtin_amdgcn_cvt_pk_fp8_f32(f[0], f[1], 0, false);
    w = __builtin_amdgcn_cvt_pk_fp8_f32(f[2], f[3], w, true);
    h8[id] = w;
}

// ---------------- aggregation: fp8 gather, 16 lanes per node, predicated unroll-8 ----------------
// h8 [N][16] uint2 rows (128 B). Each 16-lane group owns one node; 8 clamped-index gathers
// in flight per iteration, invalid slots zero-masked (fp8 0x00 == 0.0).

__global__ __launch_bounds__(256) void agg_fp8_kernel(const unsigned* __restrict__ h8,
                                                      unsigned* __restrict__ agg,
                                                      const int* __restrict__ rp,
                                                      const int* __restrict__ csr,
                                                      const float* __restrict__ degf, int N) {
    int t = threadIdx.x;
    int col = t & 15;
    int i = blockIdx.x * 16 + (t >> 4);   // 16 nodes per 256-thread block
    if (i >= N) return;
    int start = rp[i], end = rp[i + 1];
    int deg = end - start;
    const uint2* h2 = (const uint2*)h8;
    if (deg == 0) {
        uint2 v = h2[(size_t)i * 16 + col];
        floatx2 l0 = __builtin_amdgcn_cvt_pk_f32_fp8(v.x, false);
        floatx2 h0 = __builtin_amdgcn_cvt_pk_f32_fp8(v.x, true);
        floatx2 l1 = __builtin_amdgcn_cvt_pk_f32_fp8(v.y, false);
        floatx2 h1 = __builtin_amdgcn_cvt_pk_f32_fp8(v.y, true);
        uint4 r;
        r.x = pack_bf2(l0[0], l0[1]);
        r.y = pack_bf2(h0[0], h0[1]);
        r.z = pack_bf2(l1[0], l1[1]);
        r.w = pack_bf2(h1[0], h1[1]);
        ((uint4*)agg)[(size_t)i * 16 + col] = r;
        return;
    }
    floatx2 a0 = {0.f, 0.f}, a1 = {0.f, 0.f}, a2 = {0.f, 0.f}, a3 = {0.f, 0.f};
    float dsum = 0.f;
    for (int p = start; p < end; p += 8) {
        int idx[8];
        uint2 v[8];
        #pragma unroll
        for (int j = 0; j < 8; ++j) idx[j] = csr[min(p + j, end - 1)];
        #pragma unroll
        for (int j = 0; j < 8; ++j) v[j] = h2[(size_t)idx[j] * 16 + col];
        if (degf && col == 0) {
            #pragma unroll
            for (int j = 0; j < 8; ++j)
                if (p + j < end) dsum += degf[idx[j]];
        }
        #pragma unroll
        for (int j = 0; j < 8; ++j) {
            bool ok = (p + j) < end;
            unsigned vx = ok ? v[j].x : 0u;
            unsigned vy = ok ? v[j].y : 0u;
            a0 += __builtin_amdgcn_cvt_pk_f32_fp8(vx, false);
            a1 += __builtin_amdgcn_cvt_pk_f32_fp8(vx, true);
            a2 += __builtin_amdgcn_cvt_pk_f32_fp8(vy, false);
            a3 += __builtin_amdgcn_cvt_pk_f32_fp8(vy, true);
        }
    }
    if (degf && col == 0) a0[0] = dsum;   // exact neighbor-deg sum -> logical col 0 (phys byte 0)
    float inv = 1.f / (float)deg;
    uint4 r;
    r.x = pack_bf2(a0[0] * inv, a0[1] * inv);
    r.y = pack_bf2(a1[0] * inv, a1[1] * inv);
    r.z = pack_bf2(a2[0] * inv, a2[1] * inv);
    r.w = pack_bf2(a3[0] * inv, a3[1] * inv);
    ((uint4*)agg)[(size_t)i * 16 + col] = r;
}

// ---------------- GEMM: relu(A @ W^T + b) via MFMA bf16; no LDS, no barrier ----------------
// A [N,128] bf16 (phys-k order), Wb [128][64 u32] bf16 k-permuted. Lane (m,q) of wave wv
// loads its A fragment (row n0+wv*16+m, 16 B at kt*64+q*16) straight from global — same
// coalescing class as the Wb loads; L2-resident. OOB rows read in-workspace garbage that
// only lands in never-stored acc rows. Epilogue: packed permuted stores (full-line writes).

__global__ __launch_bounds__(256) void mfma_gemm_kernel(const unsigned* __restrict__ A,
                                                        unsigned* __restrict__ out8,
                                                        unsigned* __restrict__ outb,
                                                        const unsigned* __restrict__ Wb,
                                                        const float* __restrict__ bias, int N) {
    int t = threadIdx.x;
    int wv = t >> 6, lane = t & 63;
    int m = lane & 15, q = lane >> 4;
    int n0 = blockIdx.x * 64;
    const unsigned* abase = A + (size_t)(n0 + wv * 16 + m) * 64 + q * 4;

    floatx4 acc[8];
    #pragma unroll
    for (int ot = 0; ot < 8; ++ot) acc[ot] = (floatx4)(0.f);

    #pragma unroll
    for (int kt = 0; kt < 4; ++kt) {
        short8 af = *(const short8*)(abase + kt * 16);
        short8 bf[8];
        #pragma unroll
        for (int ot = 0; ot < 8; ++ot)
            bf[ot] = *(const short8*)&Wb[(ot * 16 + m) * 64 + kt * 16 + q * 4];
        #pragma unroll
        for (int ot = 0; ot < 8; ++ot)
            acc[ot] = __builtin_amdgcn_mfma_f32_16x16x32_bf16(af, bf[ot], acc[ot], 0, 0, 0);
    }

    float bv[8];
    #pragma unroll
    for (int ot = 0; ot < 8; ++ot) bv[ot] = bias[ot * 16 + m];

    #pragma unroll
    for (int r = 0; r < 4; ++r) {
        int n = n0 + wv * 16 + q * 4 + r;
        if (n < N) {
            float vv[8];
            #pragma unroll
            for (int ot = 0; ot < 8; ++ot) vv[ot] = fmaxf(acc[ot][r] + bv[ot], 0.f);
            if (out8) {
                unsigned w0 = __builtin_amdgcn_cvt_pk_fp8_f32(vv[0], vv[1], 0, false);
                w0 = __builtin_amdgcn_cvt_pk_fp8_f32(vv[2], vv[3], w0, true);
                unsigned w1 = __builtin_amdgcn_cvt_pk_fp8_f32(vv[4], vv[5], 0, false);
                w1 = __builtin_amdgcn_cvt_pk_fp8_f32(vv[6], vv[7], w1, true);
                ((uint2*)out8)[(size_t)n * 16 + m] = make_uint2(w0, w1);
            }
            if (outb) {
                uint4 w;
                w.x = pack_bf2(vv[0], vv[1]);
                w.y = pack_bf2(vv[2], vv[3]);
                w.z = pack_bf2(vv[4], vv[5]);
                w.w = pack_bf2(vv[6], vv[7]);
                ((uint4*)outb)[(size_t)n * 16 + m] = w;
            }
        }
    }
}

// ---------------- graph mean-pool + counts: 64-node blocks, 4-way node striping ----------------

__global__ __launch_bounds__(256) void pool_kernel(const unsigned* __restrict__ h,
                                                   const int* __restrict__ gid,
                                                   float* __restrict__ hg,
                                                   float* __restrict__ counts, int N) {
    int c = threadIdx.x & 63;
    int q = threadIdx.x >> 6;
    int n0 = blockIdx.x * 64;
    int nend = min(n0 + 64, N);
    float ax = 0.f, ay = 0.f, cnt = 0.f;
    int cur = -1;
    for (int n = n0 + q; n < nend; n += 4) {
        int g = gid[n];
        if (g != cur) {
            if (cur >= 0) {
                atomicAdd(&hg[cur * HID + 2 * c], ax);
                atomicAdd(&hg[cur * HID + 2 * c + 1], ay);
                if (c == 0) atomicAdd(&counts[cur], cnt);
            }
            ax = ay = cnt = 0.f;
            cur = g;
        }
        unsigned v = h[(size_t)n * 64 + c];
        ax += bf_lo(v); ay += bf_hi(v);
        cnt += 1.f;
    }
    if (cur >= 0) {
        atomicAdd(&hg[cur * HID + 2 * c], ax);
        atomicAdd(&hg[cur * HID + 2 * c + 1], ay);
        if (c == 0) atomicAdd(&counts[cur], cnt);
    }
}

// ---------------- fused classifier head (fp32), one block per graph ----------------

__global__ __launch_bounds__(128) void cls_fused_kernel(const float* __restrict__ hg,
                                                        const float* __restrict__ counts,
                                                        const float* __restrict__ Wc1p,
                                                        const float* __restrict__ Wc1,
                                                        const float* __restrict__ bc1,
                                                        const float* __restrict__ Wc2,
                                                        const float* __restrict__ bc2,
                                                        float* __restrict__ out, int G) {
    __shared__ float x[128];
    __shared__ float y[128];
    __shared__ float red[128];
    int g = blockIdx.x, t = threadIdx.x;
    float inv = 1.f / fmaxf(counts[g], 1.f);
    x[t] = hg[g * HID + t] * inv;
    __syncthreads();
    const float4* wp4 = (const float4*)(Wc1p + t * HID);
    float s = 0.f;
    #pragma unroll
    for (int k4 = 0; k4 < 32; ++k4) {
        float4 w = wp4[k4];
        s += x[k4 * 4] * w.x + x[k4 * 4 + 1] * w.y + x[k4 * 4 + 2] * w.z + x[k4 * 4 + 3] * w.w;
    }
    y[t] = s + bc1[t];
    __syncthreads();
    const float4* w4 = (const float4*)(Wc1 + t * HID);
    float s2 = 0.f;
    #pragma unroll
    for (int k4 = 0; k4 < 32; ++k4) {
        float4 w = w4[k4];
        s2 += y[k4 * 4] * w.x + y[k4 * 4 + 1] * w.y + y[k4 * 4 + 2] * w.z + y[k4 * 4 + 3] * w.w;
    }
    red[t] = (s2 + bc1[t]) * Wc2[t];
    __syncthreads();
    if (t < 64) {
        float r = red[t] + red[t + 64];
        #pragma unroll
        for (int off = 32; off > 0; off >>= 1) r += __shfl_down(r, off);
        if (t == 0) out[g] = r + bc2[0];
    }
}

// ---------------- launch ----------------

extern "C" void kernel_launch(void* const* d_in, const int* in_sizes, int n_in,
                              void* d_out, int out_size, void* d_ws, size_t ws_size,
                              hipStream_t stream) {
    const float* feat = (const float*)d_in[0];
    const int* src    = (const int*)d_in[1];
    const int* dst    = (const int*)d_in[2];
    const int* gid    = (const int*)d_in[3];
    const float* W0  = (const float*)d_in[5];
    const float* b0  = (const float*)d_in[6];
    const float* W1  = (const float*)d_in[7];
    const float* b1  = (const float*)d_in[8];
    const float* W2  = (const float*)d_in[9];
    const float* b2  = (const float*)d_in[10];
    const float* Wc1 = (const float*)d_in[11];
    const float* bc1 = (const float*)d_in[12];
    const float* Wc2 = (const float*)d_in[13];
    const float* bc2 = (const float*)d_in[14];

    const int N = in_sizes[3];
    const int E = in_sizes[1];
    const int G = out_size;
    const int NB = (N + BNODES - 1) >> BSH;

    char* ws = (char*)d_ws;
    size_t off = 0;
    auto alloc = [&](size_t bytes) { void* p = ws + off; off += (bytes + 255) & ~size_t(255); return p; };
    unsigned* h8     = (unsigned*)alloc((size_t)N * 32 * 4);   // fp8 h, permuted cols
    unsigned* hB     = (unsigned*)alloc((size_t)N * 64 * 4);   // bf16 h3, permuted cols
    unsigned* aggbuf = (unsigned*)alloc((size_t)N * 64 * 4);   // bf16 GEMM input, permuted cols
    float* degf      = (float*)alloc((size_t)N * 4);
    uint2* staging   = (uint2*)alloc((size_t)E * 8);
    int* csr         = (int*)alloc((size_t)E * 4);
    int* rp          = (int*)alloc((size_t)(N + 1) * 4);
    int* gbucket     = (int*)alloc(512 * 4);
    int* bstart      = (int*)alloc(513 * 4);
    int* gcur        = (int*)alloc(512 * 4);
    unsigned* Wb0    = (unsigned*)alloc(8192 * 4);
    unsigned* Wb1    = (unsigned*)alloc(8192 * 4);
    unsigned* Wb2    = (unsigned*)alloc(8192 * 4);
    float* Wc1p      = (float*)alloc(16384 * 4);
    float* hg        = (float*)alloc((size_t)G * HID * 4);
    float* counts    = (float*)alloc((size_t)G * 4);

    init_kernel<<<96, 256, 0, stream>>>(W0, W1, W2, Wc1, Wb0, Wb1, Wb2, Wc1p,
                                        gbucket, hg, counts, G);

    int gE = (E + 4095) / 4096;
    bucket_count_kernel<<<gE, 256, 0, stream>>>(dst, gbucket, E, NB);
    bucket_scan_kernel<<<1, 512, 0, stream>>>(gbucket, bstart, gcur, NB, E);
    bucket_scatter_kernel<<<gE, 256, 0, stream>>>(src, dst, gcur, staging, E, NB);
    csr_build_kernel<<<NB, 256, 0, stream>>>(staging, bstart, rp, csr, degf, N, E, NB);

    build_h0_kernel<<<(N * 32 + 255) / 256, 256, 0, stream>>>(feat, h8, N);

    int agg_grid = (N + 15) / 16;
    int gemm_grid = (N + 63) / 64;

    agg_fp8_kernel<<<agg_grid, 256, 0, stream>>>(h8, aggbuf, rp, csr, degf, N);
    mfma_gemm_kernel<<<gemm_grid, 256, 0, stream>>>(aggbuf, h8, nullptr, Wb0, b0, N);

    agg_fp8_kernel<<<agg_grid, 256, 0, stream>>>(h8, aggbuf, rp, csr, nullptr, N);
    mfma_gemm_kernel<<<gemm_grid, 256, 0, stream>>>(aggbuf, h8, nullptr, Wb1, b1, N);

    agg_fp8_kernel<<<agg_grid, 256, 0, stream>>>(h8, aggbuf, rp, csr, nullptr, N);
    mfma_gemm_kernel<<<gemm_grid, 256, 0, stream>>>(aggbuf, nullptr, hB, Wb2, b2, N);

    pool_kernel<<<(N + 63) / 64, 256, 0, stream>>>(hB, gid, hg, counts, N);

    cls_fused_kernel<<<G, 128, 0, stream>>>(hg, counts, Wc1p, Wc1, bc1, Wc2, bc2,
                                            (float*)d_out, G);
}

// Round 11
// 426.914 us; speedup vs baseline: 1.0210x; 1.0210x over previous
//
#include <hip/hip_runtime.h>
#include <hip/hip_bf16.h>

#define HID 128
#define NRAW 127
#define BSH 8          // 256 nodes per bucket
#define BNODES 256

// Column permutation: all hidden-state tensors (h8, aggbuf, hB, hg) store logical
// column l = ot*16+m at physical position p = m*8+ot; inverse invp(p) = (p&7)*16+(p>>3).
// GEMM weights and the first Wc1 application are k-permuted to match.

typedef __attribute__((ext_vector_type(8))) short short8;
typedef __attribute__((ext_vector_type(4))) float floatx4;
typedef __attribute__((ext_vector_type(2))) float floatx2;

__device__ inline unsigned pack_bf2(float x, float y) {
    unsigned bx = __float_as_uint(x);
    unsigned by = __float_as_uint(y);
    bx += 0x7fffu + ((bx >> 16) & 1u);   // RNE
    by += 0x7fffu + ((by >> 16) & 1u);
    return (bx >> 16) | (by & 0xffff0000u);
}
__device__ inline float bf_lo(unsigned u) { return __uint_as_float(u << 16); }
__device__ inline float bf_hi(unsigned u) { return __uint_as_float(u & 0xffff0000u); }

// ---------------- init: zeros + permuted weight packs ----------------

__global__ void init_kernel(const float* __restrict__ W0, const float* __restrict__ W1,
                            const float* __restrict__ W2, const float* __restrict__ Wc1,
                            unsigned* __restrict__ O0, unsigned* __restrict__ O1,
                            unsigned* __restrict__ O2, float* __restrict__ Wc1p,
                            int* __restrict__ gbucket, float* __restrict__ hg,
                            float* __restrict__ counts, int G) {
    int id = blockIdx.x * blockDim.x + threadIdx.x;
    if (id < 512) gbucket[id] = 0;
    if (id < G * HID) hg[id] = 0.f;
    if (id < G) counts[id] = 0.f;
    if (id < 16384) {   // Wc1 with permuted k for the first head matmul
        int t = id >> 7, p = id & 127;
        Wc1p[id] = Wc1[t * 128 + ((p & 7) * 16 + (p >> 3))];
    }
    if (id < 3 * 8192) {   // GCN weights, bf16, k-permuted
        int sel = id >> 13, l = id & 8191;
        const float* W = sel == 0 ? W0 : (sel == 1 ? W1 : W2);
        unsigned* O = sel == 0 ? O0 : (sel == 1 ? O1 : O2);
        int o = l >> 6, pp = (l & 63) * 2;
        int k0 = (pp & 7) * 16 + (pp >> 3);
        int k1 = ((pp + 1) & 7) * 16 + ((pp + 1) >> 3);
        O[l] = pack_bf2(W[o * 128 + k0], W[o * 128 + k1]);
    }
}

// ---------------- CSR build: bucketed 2-phase counting sort ----------------

__global__ __launch_bounds__(256) void bucket_count_kernel(const int* __restrict__ dst,
                                                           int* __restrict__ gbucket,
                                                           int E, int NB) {
    __shared__ int hist[512];
    int t = threadIdx.x;
    for (int b = t; b < NB; b += 256) hist[b] = 0;
    __syncthreads();
    int base = blockIdx.x * 4096;
    #pragma unroll
    for (int j = 0; j < 16; ++j) {
        int e = base + j * 256 + t;
        if (e < E) atomicAdd(&hist[dst[e] >> BSH], 1);
    }
    __syncthreads();
    for (int b = t; b < NB; b += 256) {
        int v = hist[b];
        if (v) atomicAdd(&gbucket[b], v);
    }
}

__global__ void bucket_scan_kernel(const int* __restrict__ gbucket, int* __restrict__ bstart,
                                   int* __restrict__ gcur, int NB, int E) {
    __shared__ int sm[512];
    int t = threadIdx.x;
    int v = (t < NB) ? gbucket[t] : 0;
    sm[t] = v;
    __syncthreads();
    for (int off = 1; off < 512; off <<= 1) {
        int add = (t >= off) ? sm[t - off] : 0;
        __syncthreads();
        sm[t] += add;
        __syncthreads();
    }
    if (t < NB) {
        int ex = sm[t] - v;
        bstart[t] = ex;
        gcur[t] = ex;
    }
    if (t == 0) bstart[NB] = E;
}

__global__ __launch_bounds__(256) void bucket_scatter_kernel(const int* __restrict__ src,
                                                             const int* __restrict__ dst,
                                                             int* __restrict__ gcur,
                                                             uint2* __restrict__ staging,
                                                             int E, int NB) {
    __shared__ int hist[512];
    __shared__ int base[512];
    int t = threadIdx.x;
    for (int b = t; b < NB; b += 256) hist[b] = 0;
    __syncthreads();
    int s[16], d[16], r[16];
    int e0 = blockIdx.x * 4096;
    #pragma unroll
    for (int j = 0; j < 16; ++j) {
        int e = e0 + j * 256 + t;
        if (e < E) {
            s[j] = src[e];
            d[j] = dst[e];
            r[j] = atomicAdd(&hist[d[j] >> BSH], 1);
        } else d[j] = -1;
    }
    __syncthreads();
    for (int b = t; b < NB; b += 256) {
        int v = hist[b];
        base[b] = v ? atomicAdd(&gcur[b], v) : 0;
    }
    __syncthreads();
    #pragma unroll
    for (int j = 0; j < 16; ++j) {
        if (d[j] >= 0) {
            int b = d[j] >> BSH;
            staging[base[b] + r[j]] = make_uint2((unsigned)s[j], (unsigned)d[j]);
        }
    }
}

__global__ __launch_bounds__(256) void csr_build_kernel(const uint2* __restrict__ staging,
                                                        const int* __restrict__ bstart,
                                                        int* __restrict__ rp, int* __restrict__ csr,
                                                        float* __restrict__ degf,
                                                        int N, int E, int NB) {
    __shared__ int hist[256];
    __shared__ int sm[256];
    __shared__ int excl[256];
    __shared__ int cnt[256];
    int t = threadIdx.x;
    int b = blockIdx.x;
    int nbase = b << BSH;
    int s0 = bstart[b], e1 = bstart[b + 1];
    hist[t] = 0;
    __syncthreads();
    for (int i = s0 + t; i < e1; i += 256) {
        uint2 p = staging[i];
        atomicAdd(&hist[p.y & (BNODES - 1)], 1);
    }
    __syncthreads();
    int h = hist[t];
    sm[t] = h;
    __syncthreads();
    for (int off = 1; off < 256; off <<= 1) {
        int add = (t >= off) ? sm[t - off] : 0;
        __syncthreads();
        sm[t] += add;
        __syncthreads();
    }
    excl[t] = sm[t] - h;
    cnt[t] = 0;
    int n = nbase + t;
    if (n < N) {
        rp[n] = s0 + (sm[t] - h);
        degf[n] = (float)h;
    }
    if (b == NB - 1 && t == 0) rp[N] = E;
    __syncthreads();
    for (int i = s0 + t; i < e1; i += 256) {
        uint2 p = staging[i];
        int dl = p.y & (BNODES - 1);
        int pos = s0 + excl[dl] + atomicAdd(&cnt[dl], 1);
        csr[pos] = (int)p.x;
    }
}

// ---------------- h0 in fp8, permuted layout (logical col0 zeroed; deg exact via degf) ----------------

__global__ void build_h0_kernel(const float* __restrict__ feat,
                                unsigned* __restrict__ h8, int N) {
    int id = blockIdx.x * blockDim.x + threadIdx.x;
    if (id >= N * 32) return;
    int n = id >> 5, c = id & 31;
    const float* fr = feat + (size_t)n * NRAW;
    int base = c >> 1, hb = (c & 1) * 4;
    float f[4];
    #pragma unroll
    for (int j = 0; j < 4; ++j) {
        int l = (hb + j) * 16 + base;   // logical col at physical byte 4c+j
        f[j] = (l == 0) ? 0.f : fr[l - 1];
    }
    unsigned w = __builtin_amdgcn_cvt_pk_fp8_f32(f[0], f[1], 0, false);
    w = __builtin_amdgcn_cvt_pk_fp8_f32(f[2], f[3], w, true);
    h8[id] = w;
}

// ---------------- aggregation: fp8 gather, 16 lanes per node, unroll-4 (R8 form) ----------------
// h8 [N][16] uint2 rows (128 B). Each 16-lane group owns one node, walks its CSR segment
// with 4 rows in flight; scalar tail. Low VGPR -> high occupancy (latency-bound regime).

__global__ __launch_bounds__(256) void agg_fp8_kernel(const unsigned* __restrict__ h8,
                                                      unsigned* __restrict__ agg,
                                                      const int* __restrict__ rp,
                                                      const int* __restrict__ csr,
                                                      const float* __restrict__ degf, int N) {
    int t = threadIdx.x;
    int col = t & 15;
    int i = blockIdx.x * 16 + (t >> 4);   // 16 nodes per 256-thread block
    if (i >= N) return;
    int start = rp[i], end = rp[i + 1];
    int deg = end - start;
    const uint2* h2 = (const uint2*)h8;
    if (deg == 0) {
        uint2 v = h2[(size_t)i * 16 + col];
        floatx2 l0 = __builtin_amdgcn_cvt_pk_f32_fp8(v.x, false);
        floatx2 h0 = __builtin_amdgcn_cvt_pk_f32_fp8(v.x, true);
        floatx2 l1 = __builtin_amdgcn_cvt_pk_f32_fp8(v.y, false);
        floatx2 h1 = __builtin_amdgcn_cvt_pk_f32_fp8(v.y, true);
        uint4 r;
        r.x = pack_bf2(l0[0], l0[1]);
        r.y = pack_bf2(h0[0], h0[1]);
        r.z = pack_bf2(l1[0], l1[1]);
        r.w = pack_bf2(h1[0], h1[1]);
        ((uint4*)agg)[(size_t)i * 16 + col] = r;
        return;
    }
    floatx2 a0 = {0.f, 0.f}, a1 = {0.f, 0.f}, a2 = {0.f, 0.f}, a3 = {0.f, 0.f};
    float dsum = 0.f;
    int p = start;
    for (; p + 4 <= end; p += 4) {
        int i0 = csr[p];
        int i1 = csr[p + 1];
        int i2 = csr[p + 2];
        int i3 = csr[p + 3];
        uint2 v0 = h2[(size_t)i0 * 16 + col];
        uint2 v1 = h2[(size_t)i1 * 16 + col];
        uint2 v2 = h2[(size_t)i2 * 16 + col];
        uint2 v3 = h2[(size_t)i3 * 16 + col];
        if (degf && col == 0) dsum += degf[i0] + degf[i1] + degf[i2] + degf[i3];
        a0 += __builtin_amdgcn_cvt_pk_f32_fp8(v0.x, false);
        a1 += __builtin_amdgcn_cvt_pk_f32_fp8(v0.x, true);
        a2 += __builtin_amdgcn_cvt_pk_f32_fp8(v0.y, false);
        a3 += __builtin_amdgcn_cvt_pk_f32_fp8(v0.y, true);
        a0 += __builtin_amdgcn_cvt_pk_f32_fp8(v1.x, false);
        a1 += __builtin_amdgcn_cvt_pk_f32_fp8(v1.x, true);
        a2 += __builtin_amdgcn_cvt_pk_f32_fp8(v1.y, false);
        a3 += __builtin_amdgcn_cvt_pk_f32_fp8(v1.y, true);
        a0 += __builtin_amdgcn_cvt_pk_f32_fp8(v2.x, false);
        a1 += __builtin_amdgcn_cvt_pk_f32_fp8(v2.x, true);
        a2 += __builtin_amdgcn_cvt_pk_f32_fp8(v2.y, false);
        a3 += __builtin_amdgcn_cvt_pk_f32_fp8(v2.y, true);
        a0 += __builtin_amdgcn_cvt_pk_f32_fp8(v3.x, false);
        a1 += __builtin_amdgcn_cvt_pk_f32_fp8(v3.x, true);
        a2 += __builtin_amdgcn_cvt_pk_f32_fp8(v3.y, false);
        a3 += __builtin_amdgcn_cvt_pk_f32_fp8(v3.y, true);
    }
    for (; p < end; ++p) {
        int i0 = csr[p];
        uint2 v0 = h2[(size_t)i0 * 16 + col];
        if (degf && col == 0) dsum += degf[i0];
        a0 += __builtin_amdgcn_cvt_pk_f32_fp8(v0.x, false);
        a1 += __builtin_amdgcn_cvt_pk_f32_fp8(v0.x, true);
        a2 += __builtin_amdgcn_cvt_pk_f32_fp8(v0.y, false);
        a3 += __builtin_amdgcn_cvt_pk_f32_fp8(v0.y, true);
    }
    if (degf && col == 0) a0[0] = dsum;   // exact neighbor-deg sum -> logical col 0 (phys byte 0)
    float inv = 1.f / (float)deg;
    uint4 r;
    r.x = pack_bf2(a0[0] * inv, a0[1] * inv);
    r.y = pack_bf2(a1[0] * inv, a1[1] * inv);
    r.z = pack_bf2(a2[0] * inv, a2[1] * inv);
    r.w = pack_bf2(a3[0] * inv, a3[1] * inv);
    ((uint4*)agg)[(size_t)i * 16 + col] = r;
}

// ---------------- GEMM: relu(A @ W^T + b) via MFMA bf16; no LDS, no barrier ----------------
// A [N,128] bf16 (phys-k order), Wb [128][64 u32] bf16 k-permuted. Lane (m,q) of wave wv
// loads its A fragment straight from global (L2-resident, same coalescing class as Wb).
// OOB rows read in-workspace garbage that only lands in never-stored acc rows.
// Epilogue: packed permuted stores (full-line writes).

__global__ __launch_bounds__(256) void mfma_gemm_kernel(const unsigned* __restrict__ A,
                                                        unsigned* __restrict__ out8,
                                                        unsigned* __restrict__ outb,
                                                        const unsigned* __restrict__ Wb,
                                                        const float* __restrict__ bias, int N) {
    int t = threadIdx.x;
    int wv = t >> 6, lane = t & 63;
    int m = lane & 15, q = lane >> 4;
    int n0 = blockIdx.x * 64;
    const unsigned* abase = A + (size_t)(n0 + wv * 16 + m) * 64 + q * 4;

    floatx4 acc[8];
    #pragma unroll
    for (int ot = 0; ot < 8; ++ot) acc[ot] = (floatx4)(0.f);

    #pragma unroll
    for (int kt = 0; kt < 4; ++kt) {
        short8 af = *(const short8*)(abase + kt * 16);
        short8 bf[8];
        #pragma unroll
        for (int ot = 0; ot < 8; ++ot)
            bf[ot] = *(const short8*)&Wb[(ot * 16 + m) * 64 + kt * 16 + q * 4];
        #pragma unroll
        for (int ot = 0; ot < 8; ++ot)
            acc[ot] = __builtin_amdgcn_mfma_f32_16x16x32_bf16(af, bf[ot], acc[ot], 0, 0, 0);
    }

    float bv[8];
    #pragma unroll
    for (int ot = 0; ot < 8; ++ot) bv[ot] = bias[ot * 16 + m];

    #pragma unroll
    for (int r = 0; r < 4; ++r) {
        int n = n0 + wv * 16 + q * 4 + r;
        if (n < N) {
            float vv[8];
            #pragma unroll
            for (int ot = 0; ot < 8; ++ot) vv[ot] = fmaxf(acc[ot][r] + bv[ot], 0.f);
            if (out8) {
                unsigned w0 = __builtin_amdgcn_cvt_pk_fp8_f32(vv[0], vv[1], 0, false);
                w0 = __builtin_amdgcn_cvt_pk_fp8_f32(vv[2], vv[3], w0, true);
                unsigned w1 = __builtin_amdgcn_cvt_pk_fp8_f32(vv[4], vv[5], 0, false);
                w1 = __builtin_amdgcn_cvt_pk_fp8_f32(vv[6], vv[7], w1, true);
                ((uint2*)out8)[(size_t)n * 16 + m] = make_uint2(w0, w1);
            }
            if (outb) {
                uint4 w;
                w.x = pack_bf2(vv[0], vv[1]);
                w.y = pack_bf2(vv[2], vv[3]);
                w.z = pack_bf2(vv[4], vv[5]);
                w.w = pack_bf2(vv[6], vv[7]);
                ((uint4*)outb)[(size_t)n * 16 + m] = w;
            }
        }
    }
}

// ---------------- graph mean-pool + counts: 64-node blocks, 4-way node striping ----------------

__global__ __launch_bounds__(256) void pool_kernel(const unsigned* __restrict__ h,
                                                   const int* __restrict__ gid,
                                                   float* __restrict__ hg,
                                                   float* __restrict__ counts, int N) {
    int c = threadIdx.x & 63;
    int q = threadIdx.x >> 6;
    int n0 = blockIdx.x * 64;
    int nend = min(n0 + 64, N);
    float ax = 0.f, ay = 0.f, cnt = 0.f;
    int cur = -1;
    for (int n = n0 + q; n < nend; n += 4) {
        int g = gid[n];
        if (g != cur) {
            if (cur >= 0) {
                atomicAdd(&hg[cur * HID + 2 * c], ax);
                atomicAdd(&hg[cur * HID + 2 * c + 1], ay);
                if (c == 0) atomicAdd(&counts[cur], cnt);
            }
            ax = ay = cnt = 0.f;
            cur = g;
        }
        unsigned v = h[(size_t)n * 64 + c];
        ax += bf_lo(v); ay += bf_hi(v);
        cnt += 1.f;
    }
    if (cur >= 0) {
        atomicAdd(&hg[cur * HID + 2 * c], ax);
        atomicAdd(&hg[cur * HID + 2 * c + 1], ay);
        if (c == 0) atomicAdd(&counts[cur], cnt);
    }
}

// ---------------- fused classifier head (fp32), one block per graph ----------------

__global__ __launch_bounds__(128) void cls_fused_kernel(const float* __restrict__ hg,
                                                        const float* __restrict__ counts,
                                                        const float* __restrict__ Wc1p,
                                                        const float* __restrict__ Wc1,
                                                        const float* __restrict__ bc1,
                                                        const float* __restrict__ Wc2,
                                                        const float* __restrict__ bc2,
                                                        float* __restrict__ out, int G) {
    __shared__ float x[128];
    __shared__ float y[128];
    __shared__ float red[128];
    int g = blockIdx.x, t = threadIdx.x;
    float inv = 1.f / fmaxf(counts[g], 1.f);
    x[t] = hg[g * HID + t] * inv;
    __syncthreads();
    const float4* wp4 = (const float4*)(Wc1p + t * HID);
    float s = 0.f;
    #pragma unroll
    for (int k4 = 0; k4 < 32; ++k4) {
        float4 w = wp4[k4];
        s += x[k4 * 4] * w.x + x[k4 * 4 + 1] * w.y + x[k4 * 4 + 2] * w.z + x[k4 * 4 + 3] * w.w;
    }
    y[t] = s + bc1[t];
    __syncthreads();
    const float4* w4 = (const float4*)(Wc1 + t * HID);
    float s2 = 0.f;
    #pragma unroll
    for (int k4 = 0; k4 < 32; ++k4) {
        float4 w = w4[k4];
        s2 += y[k4 * 4] * w.x + y[k4 * 4 + 1] * w.y + y[k4 * 4 + 2] * w.z + y[k4 * 4 + 3] * w.w;
    }
    red[t] = (s2 + bc1[t]) * Wc2[t];
    __syncthreads();
    if (t < 64) {
        float r = red[t] + red[t + 64];
        #pragma unroll
        for (int off = 32; off > 0; off >>= 1) r += __shfl_down(r, off);
        if (t == 0) out[g] = r + bc2[0];
    }
}

// ---------------- launch ----------------

extern "C" void kernel_launch(void* const* d_in, const int* in_sizes, int n_in,
                              void* d_out, int out_size, void* d_ws, size_t ws_size,
                              hipStream_t stream) {
    const float* feat = (const float*)d_in[0];
    const int* src    = (const int*)d_in[1];
    const int* dst    = (const int*)d_in[2];
    const int* gid    = (const int*)d_in[3];
    const float* W0  = (const float*)d_in[5];
    const float* b0  = (const float*)d_in[6];
    const float* W1  = (const float*)d_in[7];
    const float* b1  = (const float*)d_in[8];
    const float* W2  = (const float*)d_in[9];
    const float* b2  = (const float*)d_in[10];
    const float* Wc1 = (const float*)d_in[11];
    const float* bc1 = (const float*)d_in[12];
    const float* Wc2 = (const float*)d_in[13];
    const float* bc2 = (const float*)d_in[14];

    const int N = in_sizes[3];
    const int E = in_sizes[1];
    const int G = out_size;
    const int NB = (N + BNODES - 1) >> BSH;

    char* ws = (char*)d_ws;
    size_t off = 0;
    auto alloc = [&](size_t bytes) { void* p = ws + off; off += (bytes + 255) & ~size_t(255); return p; };
    unsigned* h8     = (unsigned*)alloc((size_t)N * 32 * 4);   // fp8 h, permuted cols
    unsigned* hB     = (unsigned*)alloc((size_t)N * 64 * 4);   // bf16 h3, permuted cols
    unsigned* aggbuf = (unsigned*)alloc((size_t)N * 64 * 4);   // bf16 GEMM input, permuted cols
    float* degf      = (float*)alloc((size_t)N * 4);
    uint2* staging   = (uint2*)alloc((size_t)E * 8);
    int* csr         = (int*)alloc((size_t)E * 4);
    int* rp          = (int*)alloc((size_t)(N + 1) * 4);
    int* gbucket     = (int*)alloc(512 * 4);
    int* bstart      = (int*)alloc(513 * 4);
    int* gcur        = (int*)alloc(512 * 4);
    unsigned* Wb0    = (unsigned*)alloc(8192 * 4);
    unsigned* Wb1    = (unsigned*)alloc(8192 * 4);
    unsigned* Wb2    = (unsigned*)alloc(8192 * 4);
    float* Wc1p      = (float*)alloc(16384 * 4);
    float* hg        = (float*)alloc((size_t)G * HID * 4);
    float* counts    = (float*)alloc((size_t)G * 4);

    init_kernel<<<96, 256, 0, stream>>>(W0, W1, W2, Wc1, Wb0, Wb1, Wb2, Wc1p,
                                        gbucket, hg, counts, G);

    int gE = (E + 4095) / 4096;
    bucket_count_kernel<<<gE, 256, 0, stream>>>(dst, gbucket, E, NB);
    bucket_scan_kernel<<<1, 512, 0, stream>>>(gbucket, bstart, gcur, NB, E);
    bucket_scatter_kernel<<<gE, 256, 0, stream>>>(src, dst, gcur, staging, E, NB);
    csr_build_kernel<<<NB, 256, 0, stream>>>(staging, bstart, rp, csr, degf, N, E, NB);

    build_h0_kernel<<<(N * 32 + 255) / 256, 256, 0, stream>>>(feat, h8, N);

    int agg_grid = (N + 15) / 16;
    int gemm_grid = (N + 63) / 64;

    agg_fp8_kernel<<<agg_grid, 256, 0, stream>>>(h8, aggbuf, rp, csr, degf, N);
    mfma_gemm_kernel<<<gemm_grid, 256, 0, stream>>>(aggbuf, h8, nullptr, Wb0, b0, N);

    agg_fp8_kernel<<<agg_grid, 256, 0, stream>>>(h8, aggbuf, rp, csr, nullptr, N);
    mfma_gemm_kernel<<<gemm_grid, 256, 0, stream>>>(aggbuf, h8, nullptr, Wb1, b1, N);

    agg_fp8_kernel<<<agg_grid, 256, 0, stream>>>(h8, aggbuf, rp, csr, nullptr, N);
    mfma_gemm_kernel<<<gemm_grid, 256, 0, stream>>>(aggbuf, nullptr, hB, Wb2, b2, N);

    pool_kernel<<<(N + 63) / 64, 256, 0, stream>>>(hB, gid, hg, counts, N);

    cls_fused_kernel<<<G, 128, 0, stream>>>(hg, counts, Wc1p, Wc1, bc1, Wc2, bc2,
                                            (float*)d_out, G);
}

// Round 12
// 382.606 us; speedup vs baseline: 1.1392x; 1.1158x over previous
//
#include <hip/hip_runtime.h>
#include <hip/hip_bf16.h>

#define HID 128
#define NRAW 127
#define BSH 8          // 256 nodes per bucket
#define BNODES 256

// Column permutation: all hidden-state tensors (h8a/h8b, hB, hg) store logical
// column l = ot*16+m at physical position p = m*8+ot; inverse invp(p) = (p&7)*16+(p>>3).
// GEMM weights and the first Wc1 application are k-permuted to match.

typedef __attribute__((ext_vector_type(8))) short short8;
typedef __attribute__((ext_vector_type(4))) float floatx4;
typedef __attribute__((ext_vector_type(2))) float floatx2;

__device__ inline unsigned pack_bf2(float x, float y) {
    unsigned bx = __float_as_uint(x);
    unsigned by = __float_as_uint(y);
    bx += 0x7fffu + ((bx >> 16) & 1u);   // RNE
    by += 0x7fffu + ((by >> 16) & 1u);
    return (bx >> 16) | (by & 0xffff0000u);
}
__device__ inline float bf_lo(unsigned u) { return __uint_as_float(u << 16); }
__device__ inline float bf_hi(unsigned u) { return __uint_as_float(u & 0xffff0000u); }

// ---------------- init: zeros + permuted weight packs ----------------

__global__ void init_kernel(const float* __restrict__ W0, const float* __restrict__ W1,
                            const float* __restrict__ W2, const float* __restrict__ Wc1,
                            unsigned* __restrict__ O0, unsigned* __restrict__ O1,
                            unsigned* __restrict__ O2, float* __restrict__ Wc1p,
                            int* __restrict__ gbucket, float* __restrict__ hg,
                            float* __restrict__ counts, int G) {
    int id = blockIdx.x * blockDim.x + threadIdx.x;
    if (id < 512) gbucket[id] = 0;
    if (id < G * HID) hg[id] = 0.f;
    if (id < G) counts[id] = 0.f;
    if (id < 16384) {   // Wc1 with permuted k for the first head matmul
        int t = id >> 7, p = id & 127;
        Wc1p[id] = Wc1[t * 128 + ((p & 7) * 16 + (p >> 3))];
    }
    if (id < 3 * 8192) {   // GCN weights, bf16, k-permuted
        int sel = id >> 13, l = id & 8191;
        const float* W = sel == 0 ? W0 : (sel == 1 ? W1 : W2);
        unsigned* O = sel == 0 ? O0 : (sel == 1 ? O1 : O2);
        int o = l >> 6, pp = (l & 63) * 2;
        int k0 = (pp & 7) * 16 + (pp >> 3);
        int k1 = ((pp + 1) & 7) * 16 + ((pp + 1) >> 3);
        O[l] = pack_bf2(W[o * 128 + k0], W[o * 128 + k1]);
    }
}

// ---------------- CSR build: bucketed 2-phase counting sort ----------------

__global__ __launch_bounds__(256) void bucket_count_kernel(const int* __restrict__ dst,
                                                           int* __restrict__ gbucket,
                                                           int E, int NB) {
    __shared__ int hist[512];
    int t = threadIdx.x;
    for (int b = t; b < NB; b += 256) hist[b] = 0;
    __syncthreads();
    int base = blockIdx.x * 4096;
    #pragma unroll
    for (int j = 0; j < 16; ++j) {
        int e = base + j * 256 + t;
        if (e < E) atomicAdd(&hist[dst[e] >> BSH], 1);
    }
    __syncthreads();
    for (int b = t; b < NB; b += 256) {
        int v = hist[b];
        if (v) atomicAdd(&gbucket[b], v);
    }
}

__global__ void bucket_scan_kernel(const int* __restrict__ gbucket, int* __restrict__ bstart,
                                   int* __restrict__ gcur, int NB, int E) {
    __shared__ int sm[512];
    int t = threadIdx.x;
    int v = (t < NB) ? gbucket[t] : 0;
    sm[t] = v;
    __syncthreads();
    for (int off = 1; off < 512; off <<= 1) {
        int add = (t >= off) ? sm[t - off] : 0;
        __syncthreads();
        sm[t] += add;
        __syncthreads();
    }
    if (t < NB) {
        int ex = sm[t] - v;
        bstart[t] = ex;
        gcur[t] = ex;
    }
    if (t == 0) bstart[NB] = E;
}

__global__ __launch_bounds__(256) void bucket_scatter_kernel(const int* __restrict__ src,
                                                             const int* __restrict__ dst,
                                                             int* __restrict__ gcur,
                                                             uint2* __restrict__ staging,
                                                             int E, int NB) {
    __shared__ int hist[512];
    __shared__ int base[512];
    int t = threadIdx.x;
    for (int b = t; b < NB; b += 256) hist[b] = 0;
    __syncthreads();
    int s[16], d[16], r[16];
    int e0 = blockIdx.x * 4096;
    #pragma unroll
    for (int j = 0; j < 16; ++j) {
        int e = e0 + j * 256 + t;
        if (e < E) {
            s[j] = src[e];
            d[j] = dst[e];
            r[j] = atomicAdd(&hist[d[j] >> BSH], 1);
        } else d[j] = -1;
    }
    __syncthreads();
    for (int b = t; b < NB; b += 256) {
        int v = hist[b];
        base[b] = v ? atomicAdd(&gcur[b], v) : 0;
    }
    __syncthreads();
    #pragma unroll
    for (int j = 0; j < 16; ++j) {
        if (d[j] >= 0) {
            int b = d[j] >> BSH;
            staging[base[b] + r[j]] = make_uint2((unsigned)s[j], (unsigned)d[j]);
        }
    }
}

__global__ __launch_bounds__(256) void csr_build_kernel(const uint2* __restrict__ staging,
                                                        const int* __restrict__ bstart,
                                                        int* __restrict__ rp, int* __restrict__ csr,
                                                        float* __restrict__ degf,
                                                        int N, int E, int NB) {
    __shared__ int hist[256];
    __shared__ int sm[256];
    __shared__ int excl[256];
    __shared__ int cnt[256];
    int t = threadIdx.x;
    int b = blockIdx.x;
    int nbase = b << BSH;
    int s0 = bstart[b], e1 = bstart[b + 1];
    hist[t] = 0;
    __syncthreads();
    for (int i = s0 + t; i < e1; i += 256) {
        uint2 p = staging[i];
        atomicAdd(&hist[p.y & (BNODES - 1)], 1);
    }
    __syncthreads();
    int h = hist[t];
    sm[t] = h;
    __syncthreads();
    for (int off = 1; off < 256; off <<= 1) {
        int add = (t >= off) ? sm[t - off] : 0;
        __syncthreads();
        sm[t] += add;
        __syncthreads();
    }
    excl[t] = sm[t] - h;
    cnt[t] = 0;
    int n = nbase + t;
    if (n < N) {
        rp[n] = s0 + (sm[t] - h);
        degf[n] = (float)h;
    }
    if (b == NB - 1 && t == 0) rp[N] = E;
    __syncthreads();
    for (int i = s0 + t; i < e1; i += 256) {
        uint2 p = staging[i];
        int dl = p.y & (BNODES - 1);
        int pos = s0 + excl[dl] + atomicAdd(&cnt[dl], 1);
        csr[pos] = (int)p.x;
    }
}

// ---------------- h0 in fp8, permuted layout (logical col0 zeroed; deg exact via degf) ----------------

__global__ void build_h0_kernel(const float* __restrict__ feat,
                                unsigned* __restrict__ h8, int N) {
    int id = blockIdx.x * blockDim.x + threadIdx.x;
    if (id >= N * 32) return;
    int n = id >> 5, c = id & 31;
    const float* fr = feat + (size_t)n * NRAW;
    int base = c >> 1, hb = (c & 1) * 4;
    float f[4];
    #pragma unroll
    for (int j = 0; j < 4; ++j) {
        int l = (hb + j) * 16 + base;   // logical col at physical byte 4c+j
        f[j] = (l == 0) ? 0.f : fr[l - 1];
    }
    unsigned w = __builtin_amdgcn_cvt_pk_fp8_f32(f[0], f[1], 0, false);
    w = __builtin_amdgcn_cvt_pk_fp8_f32(f[2], f[3], w, true);
    h8[id] = w;
}

// ---------------- fused GCN layer: agg (R8 unroll-4) -> LDS A-tile -> MFMA -> coalesced store ----
// 16 nodes per 256-thread block. Agg phase: 16-lane group per node, uint4 result = A-fragment
// slice (phys bf16 cols 8*col..8*col+7) -> LDS Al[16][16 uint4] (4 KB). One barrier. GEMM phase:
// wave wv computes output tiles ot=2wv,2wv+1; A-frags from LDS, B-frags from global Wb (L2-hot).
// Epilogue stages C in LDS (Cs), second barrier, then full coalesced line writes.
// If degf != null (layer 0), logical col0 of the mean is exact from degf.

__global__ __launch_bounds__(256) void gcn_fused_kernel(const unsigned* __restrict__ h8,
                                                        unsigned* __restrict__ out8,
                                                        unsigned* __restrict__ outb,
                                                        const unsigned* __restrict__ Wb,
                                                        const float* __restrict__ bias,
                                                        const int* __restrict__ rp,
                                                        const int* __restrict__ csr,
                                                        const float* __restrict__ degf, int N) {
    __shared__ unsigned Al[16 * 64];   // A tile: node g, uint4 col -> Al[(g*16+col)*4]
    __shared__ unsigned Cs[16 * 64];   // C staging (bf16: 64 u32/row; fp8: 32 u32/row)
    int t = threadIdx.x;
    int col = t & 15;
    int g = t >> 4;
    int n0 = blockIdx.x * 16;
    int i = n0 + g;
    const uint2* h2 = (const uint2*)h8;

    if (i < N) {
        int start = rp[i], end = rp[i + 1];
        int deg = end - start;
        uint4 r;
        if (deg == 0) {
            uint2 v = h2[(size_t)i * 16 + col];
            floatx2 l0 = __builtin_amdgcn_cvt_pk_f32_fp8(v.x, false);
            floatx2 h0 = __builtin_amdgcn_cvt_pk_f32_fp8(v.x, true);
            floatx2 l1 = __builtin_amdgcn_cvt_pk_f32_fp8(v.y, false);
            floatx2 h1 = __builtin_amdgcn_cvt_pk_f32_fp8(v.y, true);
            r.x = pack_bf2(l0[0], l0[1]);
            r.y = pack_bf2(h0[0], h0[1]);
            r.z = pack_bf2(l1[0], l1[1]);
            r.w = pack_bf2(h1[0], h1[1]);
        } else {
            floatx2 a0 = {0.f, 0.f}, a1 = {0.f, 0.f}, a2 = {0.f, 0.f}, a3 = {0.f, 0.f};
            float dsum = 0.f;
            int p = start;
            for (; p + 4 <= end; p += 4) {
                int i0 = csr[p];
                int i1 = csr[p + 1];
                int i2 = csr[p + 2];
                int i3 = csr[p + 3];
                uint2 v0 = h2[(size_t)i0 * 16 + col];
                uint2 v1 = h2[(size_t)i1 * 16 + col];
                uint2 v2 = h2[(size_t)i2 * 16 + col];
                uint2 v3 = h2[(size_t)i3 * 16 + col];
                if (degf && col == 0) dsum += degf[i0] + degf[i1] + degf[i2] + degf[i3];
                a0 += __builtin_amdgcn_cvt_pk_f32_fp8(v0.x, false);
                a1 += __builtin_amdgcn_cvt_pk_f32_fp8(v0.x, true);
                a2 += __builtin_amdgcn_cvt_pk_f32_fp8(v0.y, false);
                a3 += __builtin_amdgcn_cvt_pk_f32_fp8(v0.y, true);
                a0 += __builtin_amdgcn_cvt_pk_f32_fp8(v1.x, false);
                a1 += __builtin_amdgcn_cvt_pk_f32_fp8(v1.x, true);
                a2 += __builtin_amdgcn_cvt_pk_f32_fp8(v1.y, false);
                a3 += __builtin_amdgcn_cvt_pk_f32_fp8(v1.y, true);
                a0 += __builtin_amdgcn_cvt_pk_f32_fp8(v2.x, false);
                a1 += __builtin_amdgcn_cvt_pk_f32_fp8(v2.x, true);
                a2 += __builtin_amdgcn_cvt_pk_f32_fp8(v2.y, false);
                a3 += __builtin_amdgcn_cvt_pk_f32_fp8(v2.y, true);
                a0 += __builtin_amdgcn_cvt_pk_f32_fp8(v3.x, false);
                a1 += __builtin_amdgcn_cvt_pk_f32_fp8(v3.x, true);
                a2 += __builtin_amdgcn_cvt_pk_f32_fp8(v3.y, false);
                a3 += __builtin_amdgcn_cvt_pk_f32_fp8(v3.y, true);
            }
            for (; p < end; ++p) {
                int i0 = csr[p];
                uint2 v0 = h2[(size_t)i0 * 16 + col];
                if (degf && col == 0) dsum += degf[i0];
                a0 += __builtin_amdgcn_cvt_pk_f32_fp8(v0.x, false);
                a1 += __builtin_amdgcn_cvt_pk_f32_fp8(v0.x, true);
                a2 += __builtin_amdgcn_cvt_pk_f32_fp8(v0.y, false);
                a3 += __builtin_amdgcn_cvt_pk_f32_fp8(v0.y, true);
            }
            if (degf && col == 0) a0[0] = dsum;   // exact neighbor-deg sum -> logical col 0
            float inv = 1.f / (float)deg;
            r.x = pack_bf2(a0[0] * inv, a0[1] * inv);
            r.y = pack_bf2(a1[0] * inv, a1[1] * inv);
            r.z = pack_bf2(a2[0] * inv, a2[1] * inv);
            r.w = pack_bf2(a3[0] * inv, a3[1] * inv);
        }
        *(uint4*)&Al[(g * 16 + col) * 4] = r;
    }
    __syncthreads();

    // ---- GEMM phase ----
    int wv = t >> 6, lane = t & 63;
    int m = lane & 15, q = lane >> 4;
    floatx4 acc0 = (floatx4)(0.f), acc1 = (floatx4)(0.f);
    #pragma unroll
    for (int kt = 0; kt < 4; ++kt) {
        short8 af = *(const short8*)&Al[m * 64 + (kt * 4 + q) * 4];
        short8 b0 = *(const short8*)&Wb[((2 * wv) * 16 + m) * 64 + kt * 16 + q * 4];
        short8 b1 = *(const short8*)&Wb[((2 * wv + 1) * 16 + m) * 64 + kt * 16 + q * 4];
        acc0 = __builtin_amdgcn_mfma_f32_16x16x32_bf16(af, b0, acc0, 0, 0, 0);
        acc1 = __builtin_amdgcn_mfma_f32_16x16x32_bf16(af, b1, acc1, 0, 0, 0);
    }
    float bv0 = bias[(2 * wv) * 16 + m];
    float bv1 = bias[(2 * wv + 1) * 16 + m];
    #pragma unroll
    for (int r4 = 0; r4 < 4; ++r4) {
        int row = q * 4 + r4;
        float v0 = fmaxf(acc0[r4] + bv0, 0.f);
        float v1 = fmaxf(acc1[r4] + bv1, 0.f);
        if (out8) {
            // phys fp8 bytes m*8+2wv, m*8+2wv+1
            unsigned pk = __builtin_amdgcn_cvt_pk_fp8_f32(v0, v1, 0, false);
            *(unsigned short*)((char*)Cs + row * 128 + m * 8 + 2 * wv) = (unsigned short)pk;
        } else {
            // phys bf16 u32 index m*4+wv within row of 64 u32
            Cs[row * 64 + m * 4 + wv] = pack_bf2(v0, v1);
        }
    }
    __syncthreads();

    // ---- coalesced writeout ----
    {
        int row = t >> 4, c = t & 15;
        int n = n0 + row;
        if (n < N) {
            if (out8)
                ((uint2*)out8)[(size_t)n * 16 + c] =
                    *(const uint2*)((const char*)Cs + row * 128 + c * 8);
            else
                ((uint4*)outb)[(size_t)n * 16 + c] = *(const uint4*)&Cs[row * 64 + c * 4];
        }
    }
}

// ---------------- graph mean-pool + counts: 64-node blocks, 4-way node striping ----------------

__global__ __launch_bounds__(256) void pool_kernel(const unsigned* __restrict__ h,
                                                   const int* __restrict__ gid,
                                                   float* __restrict__ hg,
                                                   float* __restrict__ counts, int N) {
    int c = threadIdx.x & 63;
    int q = threadIdx.x >> 6;
    int n0 = blockIdx.x * 64;
    int nend = min(n0 + 64, N);
    float ax = 0.f, ay = 0.f, cnt = 0.f;
    int cur = -1;
    for (int n = n0 + q; n < nend; n += 4) {
        int g = gid[n];
        if (g != cur) {
            if (cur >= 0) {
                atomicAdd(&hg[cur * HID + 2 * c], ax);
                atomicAdd(&hg[cur * HID + 2 * c + 1], ay);
                if (c == 0) atomicAdd(&counts[cur], cnt);
            }
            ax = ay = cnt = 0.f;
            cur = g;
        }
        unsigned v = h[(size_t)n * 64 + c];
        ax += bf_lo(v); ay += bf_hi(v);
        cnt += 1.f;
    }
    if (cur >= 0) {
        atomicAdd(&hg[cur * HID + 2 * c], ax);
        atomicAdd(&hg[cur * HID + 2 * c + 1], ay);
        if (c == 0) atomicAdd(&counts[cur], cnt);
    }
}

// ---------------- fused classifier head (fp32), one block per graph ----------------

__global__ __launch_bounds__(128) void cls_fused_kernel(const float* __restrict__ hg,
                                                        const float* __restrict__ counts,
                                                        const float* __restrict__ Wc1p,
                                                        const float* __restrict__ Wc1,
                                                        const float* __restrict__ bc1,
                                                        const float* __restrict__ Wc2,
                                                        const float* __restrict__ bc2,
                                                        float* __restrict__ out, int G) {
    __shared__ float x[128];
    __shared__ float y[128];
    __shared__ float red[128];
    int g = blockIdx.x, t = threadIdx.x;
    float inv = 1.f / fmaxf(counts[g], 1.f);
    x[t] = hg[g * HID + t] * inv;
    __syncthreads();
    const float4* wp4 = (const float4*)(Wc1p + t * HID);
    float s = 0.f;
    #pragma unroll
    for (int k4 = 0; k4 < 32; ++k4) {
        float4 w = wp4[k4];
        s += x[k4 * 4] * w.x + x[k4 * 4 + 1] * w.y + x[k4 * 4 + 2] * w.z + x[k4 * 4 + 3] * w.w;
    }
    y[t] = s + bc1[t];
    __syncthreads();
    const float4* w4 = (const float4*)(Wc1 + t * HID);
    float s2 = 0.f;
    #pragma unroll
    for (int k4 = 0; k4 < 32; ++k4) {
        float4 w = w4[k4];
        s2 += y[k4 * 4] * w.x + y[k4 * 4 + 1] * w.y + y[k4 * 4 + 2] * w.z + y[k4 * 4 + 3] * w.w;
    }
    red[t] = (s2 + bc1[t]) * Wc2[t];
    __syncthreads();
    if (t < 64) {
        float r = red[t] + red[t + 64];
        #pragma unroll
        for (int off = 32; off > 0; off >>= 1) r += __shfl_down(r, off);
        if (t == 0) out[g] = r + bc2[0];
    }
}

// ---------------- launch ----------------

extern "C" void kernel_launch(void* const* d_in, const int* in_sizes, int n_in,
                              void* d_out, int out_size, void* d_ws, size_t ws_size,
                              hipStream_t stream) {
    const float* feat = (const float*)d_in[0];
    const int* src    = (const int*)d_in[1];
    const int* dst    = (const int*)d_in[2];
    const int* gid    = (const int*)d_in[3];
    const float* W0  = (const float*)d_in[5];
    const float* b0  = (const float*)d_in[6];
    const float* W1  = (const float*)d_in[7];
    const float* b1  = (const float*)d_in[8];
    const float* W2  = (const float*)d_in[9];
    const float* b2  = (const float*)d_in[10];
    const float* Wc1 = (const float*)d_in[11];
    const float* bc1 = (const float*)d_in[12];
    const float* Wc2 = (const float*)d_in[13];
    const float* bc2 = (const float*)d_in[14];

    const int N = in_sizes[3];
    const int E = in_sizes[1];
    const int G = out_size;
    const int NB = (N + BNODES - 1) >> BSH;

    char* ws = (char*)d_ws;
    size_t off = 0;
    auto alloc = [&](size_t bytes) { void* p = ws + off; off += (bytes + 255) & ~size_t(255); return p; };
    unsigned* h8a    = (unsigned*)alloc((size_t)N * 32 * 4);   // fp8 h buffer A (permuted cols)
    unsigned* h8b    = (unsigned*)alloc((size_t)N * 32 * 4);   // fp8 h buffer B
    unsigned* hB     = (unsigned*)alloc((size_t)N * 64 * 4);   // bf16 h3 for pool
    float* degf      = (float*)alloc((size_t)N * 4);
    uint2* staging   = (uint2*)alloc((size_t)E * 8);
    int* csr         = (int*)alloc((size_t)E * 4);
    int* rp          = (int*)alloc((size_t)(N + 1) * 4);
    int* gbucket     = (int*)alloc(512 * 4);
    int* bstart      = (int*)alloc(513 * 4);
    int* gcur        = (int*)alloc(512 * 4);
    unsigned* Wb0    = (unsigned*)alloc(8192 * 4);
    unsigned* Wb1    = (unsigned*)alloc(8192 * 4);
    unsigned* Wb2    = (unsigned*)alloc(8192 * 4);
    float* Wc1p      = (float*)alloc(16384 * 4);
    float* hg        = (float*)alloc((size_t)G * HID * 4);
    float* counts    = (float*)alloc((size_t)G * 4);

    init_kernel<<<96, 256, 0, stream>>>(W0, W1, W2, Wc1, Wb0, Wb1, Wb2, Wc1p,
                                        gbucket, hg, counts, G);

    int gE = (E + 4095) / 4096;
    bucket_count_kernel<<<gE, 256, 0, stream>>>(dst, gbucket, E, NB);
    bucket_scan_kernel<<<1, 512, 0, stream>>>(gbucket, bstart, gcur, NB, E);
    bucket_scatter_kernel<<<gE, 256, 0, stream>>>(src, dst, gcur, staging, E, NB);
    csr_build_kernel<<<NB, 256, 0, stream>>>(staging, bstart, rp, csr, degf, N, E, NB);

    build_h0_kernel<<<(N * 32 + 255) / 256, 256, 0, stream>>>(feat, h8a, N);

    int layer_grid = (N + 15) / 16;
    gcn_fused_kernel<<<layer_grid, 256, 0, stream>>>(h8a, h8b, nullptr, Wb0, b0, rp, csr, degf, N);
    gcn_fused_kernel<<<layer_grid, 256, 0, stream>>>(h8b, h8a, nullptr, Wb1, b1, rp, csr, nullptr, N);
    gcn_fused_kernel<<<layer_grid, 256, 0, stream>>>(h8a, nullptr, hB, Wb2, b2, rp, csr, nullptr, N);

    pool_kernel<<<(N + 63) / 64, 256, 0, stream>>>(hB, gid, hg, counts, N);

    cls_fused_kernel<<<G, 128, 0, stream>>>(hg, counts, Wc1p, Wc1, bc1, Wc2, bc2,
                                            (float*)d_out, G);
}